// Round 8
// baseline (298.583 us; speedup 1.0000x reference)
//
#include <hip/hip_runtime.h>
#include <math.h>

#define T_TOKENS 4096
#define HIDDEN   2048
#define N_EXPERTS 8
#define N_ROWS   (N_EXPERTS * T_TOKENS)   // 32768 rows of router_indices
#define ROW_F4   (HIDDEN / 4)             // 512 float4 per row

// R10. Final accounting (R5/R6/R7 over-determined): fill=~40 (never slow),
// router=~20 warm / ~70 cold (pure latency exposure), plus a ~40 us
// order-independent first-kernel-after-poison tax (TCC write-queue drain
// from the harness poison fill; R7's order swap proved it can't be
// canceled). Strategy: stop paying the router ADDITIVELY — fuse with
// role-separated blocks so the router hides entirely under fill+tax:
//   blocks 0..1023  = router-only: 1 token/wave -> 16 router waves/CU
//                     (4x the latency hiding of R4/R7's 4 waves/CU).
//   blocks 1024..2047 = fill-only: 8 rows = 64 KB contiguous per wave.
// Dispatch round-robin gives every CU ~16 router + ~16 fill waves
// concurrently; fill (~80 us incl. tax) covers even a cold router.
// W read from L1/L2 (64 KB, replicated per XCD); no LDS -> no occupancy cap.
#define NBLOCKS 2048

__global__ __launch_bounds__(256) void fused_router_fill(
    const float* __restrict__ h, const float* __restrict__ w,
    float* __restrict__ out0, float* __restrict__ out1, float* __restrict__ out2)
{
    const int bid  = blockIdx.x;
    const int wave = threadIdx.x >> 6;
    const int lane = threadIdx.x & 63;

    if (bid < 1024) {
        // --------------- router role: 1 token per wave ---------------
        const int t = bid * 4 + wave;            // 0..4095

        const float4* h4 = (const float4*)h;
        const float4* w4 = (const float4*)w;

        // issue the whole 8 KB token row up front (8 independent 1 KB loads)
        float4 hv[8];
        #pragma unroll
        for (int j = 0; j < 8; j++)
            hv[j] = h4[(size_t)t * ROW_F4 + j * 64 + lane];

        float acc[N_EXPERTS];
        #pragma unroll
        for (int e = 0; e < N_EXPERTS; e++) acc[e] = 0.f;

        #pragma unroll
        for (int e = 0; e < N_EXPERTS; e++) {
            #pragma unroll
            for (int j = 0; j < 8; j++) {
                float4 wv = w4[e * ROW_F4 + j * 64 + lane];
                acc[e] += hv[j].x * wv.x + hv[j].y * wv.y
                        + hv[j].z * wv.z + hv[j].w * wv.w;
            }
        }

        // 64-lane shuffle reduction per expert
        #pragma unroll
        for (int e = 0; e < N_EXPERTS; e++) {
            #pragma unroll
            for (int off = 32; off > 0; off >>= 1)
                acc[e] += __shfl_down(acc[e], off, 64);
        }

        if (lane == 0) {
            // top-2 of 8; strict > keeps first index on ties (== lax.top_k)
            int i1 = 0; float v1 = acc[0];
            #pragma unroll
            for (int e = 1; e < N_EXPERTS; e++)
                if (acc[e] > v1) { v1 = acc[e]; i1 = e; }
            int i2 = -1; float v2 = -INFINITY;
            #pragma unroll
            for (int e = 0; e < N_EXPERTS; e++)
                if (e != i1 && acc[e] > v2) { v2 = acc[e]; i2 = e; }

            float s1 = 1.f / (1.f + expf(-v1));
            float s2 = 1.f / (1.f + expf(-v2));

            #pragma unroll
            for (int e = 0; e < N_EXPERTS; e++) {
                float val = (e == i1) ? s1 : ((e == i2) ? s2 : 0.f);
                out0[e * T_TOKENS + t] = val;
                out2[e * T_TOKENS + t] = val;
            }
        }
    } else {
        // --------------- fill role: 8 rows = 64 KB per wave ---------------
        // Row er = e*T + t holds constant value t = er & 4095 across H.
        // Plain stores (nt bypassed L2 write-combining, 6x slower — R2).
        const int fwave = (bid - 1024) * 4 + wave;   // 0..4095
        const int r0    = fwave * 8;
        float4* o4 = (float4*)out1;

        #pragma unroll
        for (int i = 0; i < 8; i++) {
            float v = (float)((r0 + i) & (T_TOKENS - 1));
            float4 vv = make_float4(v, v, v, v);
            float4* rowp = o4 + (size_t)(r0 + i) * ROW_F4;
            #pragma unroll
            for (int j = 0; j < 8; j++)
                rowp[j * 64 + lane] = vv;
        }
    }
}

extern "C" void kernel_launch(void* const* d_in, const int* in_sizes, int n_in,
                              void* d_out, int out_size, void* d_ws, size_t ws_size,
                              hipStream_t stream) {
    const float* h = (const float*)d_in[0];   // [4096, 2048] f32
    const float* w = (const float*)d_in[1];   // [8, 2048] f32
    // d_in[2] = top_k (always 2 for this problem)

    float* out  = (float*)d_out;
    float* out0 = out;                                            // router_scores [8,4096]
    float* out1 = out + N_EXPERTS * T_TOKENS;                     // router_indices [32768,2048]
    float* out2 = out1 + (size_t)N_EXPERTS * T_TOKENS * HIDDEN;   // router_probs [32768,1]

    hipLaunchKernelGGL(fused_router_fill, dim3(NBLOCKS), dim3(256), 0, stream,
                       h, w, out0, out1, out2);
}